// Round 9
// baseline (1486.153 us; speedup 1.0000x reference)
//
#include <hip/hip_runtime.h>
#include <stdint.h>

typedef unsigned short u16;
typedef __attribute__((ext_vector_type(8))) short bf16x8;
typedef __attribute__((ext_vector_type(4))) float f32x4;

#define HD 256
#define AST 264    // LDS row stride in u16 (256 + 8 pad -> rows offset 4 banks)
#define PCAP 2048  // max corrected (backtracking) edges; expected ~16 here

static __device__ __forceinline__ float b2f(u16 x){
  union{float f; unsigned u;} v; v.u = ((unsigned)x)<<16; return v.f;
}
static __device__ __forceinline__ u16 f2b(float f){
  union{float f; unsigned u;} v; v.f = f;
  unsigned r = v.u + 0x7fffu + ((v.u>>16)&1u);
  return (u16)(r>>16);
}

// ---------------- fill int buffer ----------------
__global__ void k_fill_int(int* __restrict__ p, int n, int val){
  int i = blockIdx.x*256 + threadIdx.x;
  if (i < n) p[i] = val;
}

// ---------------- histogram ----------------
__global__ void k_hist(const int* __restrict__ key, int* __restrict__ deg, int n){
  int i = blockIdx.x*256 + threadIdx.x;
  if (i < n) atomicAdd(&deg[key[i]], 1);
}

// ---------------- single-block exclusive scan ----------------
__global__ __launch_bounds__(1024) void k_scan(const int* __restrict__ deg, int* __restrict__ start,
                                               int* __restrict__ cursor, int n){
  __shared__ int sm[1024];
  const int t = threadIdx.x;
  const int chunk = (n + 1023) >> 10;
  const int lo = t*chunk, hi = min(lo+chunk, n);
  int s = 0;
  for (int i=lo;i<hi;i++) s += deg[i];
  sm[t] = s;
  __syncthreads();
  for (int ofs=1; ofs<1024; ofs<<=1){
    int v = (t>=ofs) ? sm[t-ofs] : 0;
    __syncthreads();
    sm[t] += v;
    __syncthreads();
  }
  int base = sm[t] - s;
  for (int i=lo;i<hi;i++){
    start[i] = base; cursor[i] = base;
    base += deg[i];
  }
  if (t == 1023) start[n] = sm[1023];
}

// ---------------- fill buckets ----------------
__global__ void k_fill(const int* __restrict__ key, const int* __restrict__ val,
                       int* __restrict__ cursor, int* __restrict__ bucket, int n){
  int i = blockIdx.x*256 + threadIdx.x;
  if (i >= n) return;
  int pos = atomicAdd(&cursor[key[i]], 1);
  bucket[pos] = val ? val[i] : i;
}

// ---------------- alpha16[v] = bf16( sum_{j} tree_m[bucket[j]] ) ----------------
__global__ void k_alpha_gather(const float* __restrict__ tree_m, const int* __restrict__ start,
                               const int* __restrict__ bucket, u16* __restrict__ alpha16, int N){
  int v = (int)(((long long)blockIdx.x*blockDim.x + threadIdx.x)>>6);
  int l = threadIdx.x & 63;
  if (v >= N) return;
  int s = start[v], e2 = start[v+1];
  float a0=0.f,a1=0.f,a2=0.f,a3=0.f;
  for (int j=s;j<e2;j++){
    float4 tv = *(const float4*)(tree_m + (long long)bucket[j]*HD + l*4);
    a0 += tv.x; a1 += tv.y; a2 += tv.z; a3 += tv.w;
  }
  ushort4 o; o.x=f2b(a0); o.y=f2b(a1); o.z=f2b(a2); o.w=f2b(a3);
  *(ushort4*)(alpha16 + (long long)v*HD + l*4) = o;
}

// ---------------- frag-major B prep: BTf_bp (Wi|pad|Wh, 10 ksteps), BTf_fo (Wo ext, 10) ----
__global__ void k_prep_B(const float* __restrict__ Wi, const float* __restrict__ Wh,
                         const float* __restrict__ Wo,
                         u16* __restrict__ BTf_bp, u16* __restrict__ BTf_fo){
  int g = blockIdx.x*256 + threadIdx.x;   // 81920 total
  if (g >= 81920) return;
  int i = g & 7;
  int l = (g>>3) & 63;
  int t = g >> 9;                // 0..159
  int nj = t & 15, ks = t >> 4;  // ks 0..9
  int n = nj*16 + (l & 15);
  int k = ks*32 + (l>>4)*8 + i;
  float bp = 0.f, fo = 0.f;
  if (k < 40) bp = Wi[k*HD + n];
  else if (k >= 64) bp = Wh[(k-64)*HD + n];
  if (k < 35) fo = Wo[k*HD + n];
  else if (k >= 64) fo = Wo[(k-29)*HD + n];
  BTf_bp[g] = f2b(bp);
  BTf_fo[g] = f2b(fo);
}

// ---------------- frag-major Wh (8 ksteps, K=256) ----------------
__global__ void k_prep_Bh(const float* __restrict__ Wh, u16* __restrict__ BTf_h){
  int g = blockIdx.x*256 + threadIdx.x;   // 65536 total
  if (g >= 65536) return;
  int i = g & 7;
  int l = (g>>3) & 63;
  int t = g >> 9;                // 0..127
  int nj = t & 15, ks = t >> 4;  // ks 0..7
  int n = nj*16 + (l & 15);
  int k = ks*32 + (l>>4)*8 + i;
  BTf_h[g] = f2b(Wh[k*HD + n]);
}

// ---------------- backtracking-pair probes ----------------
// pairs for edge e2: in-edges e1 of src[e2] (via dst-CSR) with src[e1]==dst[e2]
__global__ void k_probe1(const int* __restrict__ esrc, const int* __restrict__ edst,
                         const int* __restrict__ sd, const int* __restrict__ bd,
                         int* __restrict__ degx, int E){
  int e2 = blockIdx.x*256 + threadIdx.x;
  if (e2 >= E) return;
  int v = esrc[e2], d = edst[e2], cnt = 0;
  for (int j = sd[v]; j < sd[v+1]; j++)
    if (esrc[bd[j]] == d) cnt++;
  degx[e2] = cnt;
}
__global__ void k_probe2(const int* __restrict__ esrc, const int* __restrict__ edst,
                         const int* __restrict__ sd, const int* __restrict__ bd,
                         const int* __restrict__ startx,
                         int* __restrict__ pairs, int* __restrict__ aff,
                         int* __restrict__ affE2, int* __restrict__ affcnt, int E){
  int e2 = blockIdx.x*256 + threadIdx.x;
  if (e2 >= E) return;
  int v = esrc[e2], d = edst[e2];
  int pos = startx[e2];
  int found = 0;
  for (int j = sd[v]; j < sd[v+1]; j++){
    int e1 = bd[j];
    if (esrc[e1] == d){
      if (pos < 65536) pairs[pos] = e1;
      pos++; found = 1;
    }
  }
  if (found){
    int slot = atomicAdd(affcnt, 1);
    if (slot < PCAP){ aff[e2] = slot; affE2[slot] = e2; }
  }
}

// ---------------- correction products: corrP_k[slot] = (Σ partners msg_{k-1}) @ Wh ----
__global__ void k_corr(const u16* __restrict__ mi16, const u16* __restrict__ P16,
                       const float* __restrict__ corrPp, const int* __restrict__ aff,
                       const int* __restrict__ esrc,
                       const int* __restrict__ startx, const int* __restrict__ pairs,
                       const int* __restrict__ affE2, const int* __restrict__ affcnt,
                       const float* __restrict__ Wh32, float* __restrict__ corrPc, int first){
  __shared__ float sb[4][256];
  const int wave = threadIdx.x>>6, l = threadIdx.x&63;
  const int gw = blockIdx.x*4 + wave;
  int cnt = min(*affcnt, PCAP);
  for (int s = gw; s < cnt; s += 32){
    int e2 = affE2[s];
    float a0=0.f,a1=0.f,a2=0.f,a3=0.f;
    for (int q = startx[e2]; q < startx[e2+1] && q < 65536; q++){
      int e1 = pairs[q];
      uint2 mv = *(const uint2*)(mi16 + (long long)e1*HD + l*4);
      float m0=b2f((u16)mv.x), m1=b2f((u16)(mv.x>>16)), m2=b2f((u16)mv.y), m3=b2f((u16)(mv.y>>16));
      if (!first){
        int sv = esrc[e1];
        uint2 pv = *(const uint2*)(P16 + (long long)sv*HD + l*4);
        m0+=b2f((u16)pv.x); m1+=b2f((u16)(pv.x>>16)); m2+=b2f((u16)pv.y); m3+=b2f((u16)(pv.y>>16));
        int a = aff[e1];
        if (a >= 0){
          float4 cp = *(const float4*)(corrPp + (long long)a*HD + l*4);
          m0-=cp.x; m1-=cp.y; m2-=cp.z; m3-=cp.w;
        }
      }
      a0 += m0>0.f?m0:0.f; a1 += m1>0.f?m1:0.f; a2 += m2>0.f?m2:0.f; a3 += m3>0.f?m3:0.f;
    }
    sb[wave][l*4+0]=a0; sb[wave][l*4+1]=a1; sb[wave][l*4+2]=a2; sb[wave][l*4+3]=a3;
    // wave-internal LDS exchange (no barrier needed)
    float o0=0.f,o1=0.f,o2=0.f,o3=0.f;
    for (int k=0;k<256;k++){
      float w = sb[wave][k];
      float4 wr = *(const float4*)(Wh32 + (long long)k*HD + l*4);
      o0 += w*wr.x; o1 += w*wr.y; o2 += w*wr.z; o3 += w*wr.w;
    }
    float4 o; o.x=o0; o.y=o1; o.z=o2; o.w=o3;
    *(float4*)(corrPc + (long long)s*HD + l*4) = o;
  }
}

// ---------------- node-sum: SA_k[v] = alpha[v] + Σ_{dst(e)=v} msg_{k-1}[e] ----------------
// msg on the fly: first ? relu(mi) : relu(mi + P[src e] - corrP[aff e])
__global__ void k_nodesum(const u16* __restrict__ mi16, const u16* __restrict__ P16,
                          const u16* __restrict__ alpha16,
                          const int* __restrict__ sd, const int* __restrict__ bd,
                          const int* __restrict__ esrc, const int* __restrict__ aff,
                          const float* __restrict__ corrPp,
                          u16* __restrict__ SA16, int N, int first){
  int v = (int)(((long long)blockIdx.x*blockDim.x + threadIdx.x)>>6);
  int l = threadIdx.x & 63;
  if (v >= N) return;
  float a0,a1,a2,a3;
  { uint2 av = *(const uint2*)(alpha16 + (long long)v*HD + l*4);
    a0=b2f((u16)av.x); a1=b2f((u16)(av.x>>16)); a2=b2f((u16)av.y); a3=b2f((u16)(av.y>>16)); }
  for (int j = sd[v]; j < sd[v+1]; j++){
    int e = bd[j];
    uint2 mv = *(const uint2*)(mi16 + (long long)e*HD + l*4);
    float m0=b2f((u16)mv.x), m1=b2f((u16)(mv.x>>16)), m2=b2f((u16)mv.y), m3=b2f((u16)(mv.y>>16));
    if (!first){
      int sv = esrc[e];
      uint2 pv = *(const uint2*)(P16 + (long long)sv*HD + l*4);
      m0+=b2f((u16)pv.x); m1+=b2f((u16)(pv.x>>16)); m2+=b2f((u16)pv.y); m3+=b2f((u16)(pv.y>>16));
      int a = aff[e];
      if (a >= 0){
        float4 cp = *(const float4*)(corrPp + (long long)a*HD + l*4);
        m0-=cp.x; m1-=cp.y; m2-=cp.z; m3-=cp.w;
      }
    }
    a0 += m0>0.f?m0:0.f; a1 += m1>0.f?m1:0.f; a2 += m2>0.f?m2:0.f; a3 += m3>0.f?m3:0.f;
  }
  ushort4 o; o.x=f2b(a0); o.y=f2b(a1); o.z=f2b(a2); o.w=f2b(a3);
  *(ushort4*)(SA16 + (long long)v*HD + l*4) = o;
}

// ---------------- MFMA GEMM, wave-per-16-rows, wave-private LDS, zero barriers --------
// mode 0: rows=edges, A=[x_src|xe|pad], ksteps 2 (BTf_bp),   out16 RAW  (msg_input)
// mode 3: rows=nodes, A=[SA row],       ksteps 8 (BTf_h),    out16 RAW  (P)
// mode 2: rows=nodes, A=[x_v|pad|SA],   ksteps 10 (BTf_fo),  out32 relu(+bias)
__global__ __launch_bounds__(256, 3) void k_mpnn(
    const float* __restrict__ xn, const float* __restrict__ xe,
    const u16* __restrict__ SA, const int* __restrict__ esrc,
    const u16* __restrict__ BTf, const float* __restrict__ bias,
    u16* __restrict__ out16, float* __restrict__ out32, int M, int mode)
{
  __shared__ u16 G_lds[4][16*AST];   // 33,792 B
  const int tid = threadIdx.x;
  const int wave = tid>>6, l = tid&63;
  const int lr = l&15, lq = l>>4;
  const int m0 = blockIdx.x*64 + wave*16;
  u16* Gw = G_lds[wave];

  const int rowl = m0 + lr;
  const bool rvl = rowl < M;
  int srcl = 0;
  if (mode == 0 && rvl) srcl = esrc[rowl];

  // ---- stage A into wave-private LDS (coalesced)
  if (mode == 0){
    for (int r=0; r<16; r++){
      int sv = __shfl(srcl, r);
      int rw = m0 + r;
      float v = 0.f;
      if (rw < M){
        if (l < 35) v = xn[(long long)sv*35 + l];
        else if (l < 40) v = xe[(long long)rw*5 + (l-35)];
      }
      Gw[r*AST + l] = f2b(v);
    }
  } else {
    for (int r=0; r<16; r++){
      int rw = m0 + r;
      if (rw < M){
        uint2 sa = *(const uint2*)(SA + (long long)rw*HD + l*4);
        *(uint2*)&Gw[r*AST + l*4] = sa;
      }
    }
  }

  // ---- A-frags
  bf16x8 af[10];
  if (mode == 0){
    af[0] = *(const bf16x8*)&Gw[lr*AST + lq*8];
    af[1] = *(const bf16x8*)&Gw[lr*AST + 32 + lq*8];
  } else if (mode == 3){
    #pragma unroll
    for (int ks=0; ks<8; ks++) af[ks] = *(const bf16x8*)&Gw[lr*AST + ks*32 + lq*8];
  } else {
    #pragma unroll
    for (int ks=0; ks<2; ks++){
      #pragma unroll
      for (int i=0;i<8;i++){
        int k = ks*32 + lq*8 + i;
        float v = 0.f;
        if (rvl && k < 35) v = xn[(long long)rowl*35 + k];
        af[ks][i] = (short)f2b(v);
      }
    }
    #pragma unroll
    for (int ks=0; ks<8; ks++) af[2+ks] = *(const bf16x8*)&Gw[lr*AST + ks*32 + lq*8];
  }

  // ---- MFMA, frag-major B
  f32x4 acc[16];
  #pragma unroll
  for (int nj=0;nj<16;nj++) acc[nj] = (f32x4){0.f,0.f,0.f,0.f};
  const u16* bb = BTf + l*8;
#define KS(ks) { \
    _Pragma("unroll") \
    for (int nj=0;nj<16;nj++){ \
      bf16x8 bf = *(const bf16x8*)(bb + ((ks)*16+nj)*512); \
      acc[nj] = __builtin_amdgcn_mfma_f32_16x16x32_bf16(af[ks], bf, acc[nj], 0,0,0); \
    } }
  if (mode == 0){ KS(0) KS(1) }
  else if (mode == 3){ KS(0) KS(1) KS(2) KS(3) KS(4) KS(5) KS(6) KS(7) }
  else { KS(0) KS(1) KS(2) KS(3) KS(4) KS(5) KS(6) KS(7) KS(8) KS(9) }
#undef KS

  // ---- epilogue: C/D layout col=nj*16+lr, row=lq*4+reg
  if (mode == 2){
    #pragma unroll
    for (int reg=0; reg<4; reg++){
      int gm = m0 + lq*4 + reg;
      if (gm < M){
        #pragma unroll
        for (int nj=0;nj<16;nj++){
          int col = nj*16 + lr;
          float v = acc[nj][reg] + bias[col];
          out32[(long long)gm*HD + col] = v > 0.f ? v : 0.f;
        }
      }
    }
  } else {
    // transpose through (now dead) wave slice -> coalesced row stores, RAW values
    #pragma unroll
    for (int nj=0;nj<16;nj++){
      #pragma unroll
      for (int reg=0; reg<4; reg++){
        Gw[(lq*4+reg)*AST + nj*16 + lr] = f2b(acc[nj][reg]);
      }
    }
    for (int r=0; r<16; r++){
      int gm = m0 + r;
      if (gm < M){
        uint2 v = *(const uint2*)&Gw[r*AST + l*4];
        *(uint2*)(out16 + (long long)gm*HD + l*4) = v;
      }
    }
  }
}

// ---------------- graph mean (graph_ids sorted), fp32 in/out ----------------
__global__ void k_graph_mean(const float* __restrict__ h, const int* __restrict__ gid,
                             int N, int G, float* __restrict__ out){
  int g = (int)(((long long)blockIdx.x*blockDim.x + threadIdx.x)>>6);
  int l = threadIdx.x & 63;
  if (g >= G) return;
  int lo=0, hi=N;
  while (lo<hi){ int mid=(lo+hi)>>1; if (gid[mid] < g) lo=mid+1; else hi=mid; }
  int b = lo;
  hi = N;
  while (lo<hi){ int mid=(lo+hi)>>1; if (gid[mid] < g+1) lo=mid+1; else hi=mid; }
  int e2 = lo;
  float a0=0.f,a1=0.f,a2=0.f,a3=0.f;
  for (int v=b; v<e2; v++){
    float4 hv = *(const float4*)(h + (long long)v*HD + l*4);
    a0 += hv.x; a1 += hv.y; a2 += hv.z; a3 += hv.w;
  }
  int cnt = e2 - b; if (cnt < 1) cnt = 1;
  float inv = 1.0f/(float)cnt;
  float4 o; o.x=a0*inv; o.y=a1*inv; o.z=a2*inv; o.w=a3*inv;
  *(float4*)(out + (long long)g*HD + l*4) = o;
}

extern "C" void kernel_launch(void* const* d_in, const int* in_sizes, int n_in,
                              void* d_out, int out_size, void* d_ws, size_t ws_size,
                              hipStream_t stream){
  const float* x_nodes = (const float*)d_in[0];
  const float* x_edges = (const float*)d_in[1];
  const float* tree_m  = (const float*)d_in[2];
  const float* W_i     = (const float*)d_in[3];
  const float* W_h     = (const float*)d_in[4];
  const float* W_o     = (const float*)d_in[5];
  const float* b_o     = (const float*)d_in[6];
  const int* edge_src = (const int*)d_in[7];
  const int* edge_dst = (const int*)d_in[8];
  const int* tgt      = (const int*)d_in[11];
  const int* teid     = (const int*)d_in[12];
  const int* gid      = (const int*)d_in[13];

  const int N = in_sizes[0]/35;
  const int E = in_sizes[1]/5;
  const int K = in_sizes[11];
  const int G = out_size/HD;

  // ---- workspace (~185 MB total; 231.5 MB proven safe) ----
  char* wsb = (char*)d_ws;
  size_t off = 0;
  auto alloc = [&](size_t bytes)->char*{
    char* p = wsb + off; off += (bytes + 255) & ~(size_t)255; return p;
  };
  u16*   msgIn   = (u16*)  alloc((size_t)E*HD*2);       // raw msg_input (bf16)
  u16*   alpha16 = (u16*)  alloc((size_t)N*HD*2);
  u16*   SA16    = (u16*)  alloc((size_t)N*HD*2);
  u16*   P16     = (u16*)  alloc((size_t)N*HD*2);
  u16*   BTf_bp  = (u16*)  alloc(81920*2);
  u16*   BTf_fo  = (u16*)  alloc(81920*2);
  u16*   BTf_h   = (u16*)  alloc(65536*2);
  int*   deg_d   = (int*)  alloc((size_t)(N+1)*4);
  int*   start_d = (int*)  alloc((size_t)(N+1)*4);
  int*   cur_d   = (int*)  alloc((size_t)(N+1)*4);
  int*   bucket_d= (int*)  alloc((size_t)E*4);
  int*   deg_t   = (int*)  alloc((size_t)(N+1)*4);
  int*   start_t = (int*)  alloc((size_t)(N+1)*4);
  int*   cur_t   = (int*)  alloc((size_t)(N+1)*4);
  int*   bucket_t= (int*)  alloc((size_t)K*4);
  int*   degx    = (int*)  alloc((size_t)(E+1)*4);
  int*   startx  = (int*)  alloc((size_t)(E+1)*4);
  int*   curx    = (int*)  alloc((size_t)(E+1)*4);
  int*   pairs   = (int*)  alloc(65536*4);
  int*   aff     = (int*)  alloc((size_t)E*4);
  int*   affE2   = (int*)  alloc(PCAP*4);
  int*   affcnt  = (int*)  alloc(256);
  float* corrP0  = (float*)alloc((size_t)PCAP*HD*4);
  float* corrP1  = (float*)alloc((size_t)PCAP*HD*4);
  float* hbuf    = (float*)msgIn;   // msg_input dead after last nodesum

  const int ngrid = (N+255)/256;
  const int egrid256 = (E+255)/256;
  const int kgrid256 = (K+255)/256;

  // weight prep
  k_prep_B <<<320, 256, 0, stream>>>(W_i, W_h, W_o, BTf_bp, BTf_fo);
  k_prep_Bh<<<256, 256, 0, stream>>>(W_h, BTf_h);

  // dst-CSR (needed from iteration 1 now)
  k_fill_int<<<ngrid, 256, 0, stream>>>(deg_d, N, 0);
  k_hist<<<egrid256, 256, 0, stream>>>(edge_dst, deg_d, E);
  k_scan<<<1, 1024, 0, stream>>>(deg_d, start_d, cur_d, N);
  k_fill<<<egrid256, 256, 0, stream>>>(edge_dst, (const int*)0, cur_d, bucket_d, E);

  // tgt-CSR + alpha
  k_fill_int<<<ngrid, 256, 0, stream>>>(deg_t, N, 0);
  k_hist<<<kgrid256, 256, 0, stream>>>(tgt, deg_t, K);
  k_scan<<<1, 1024, 0, stream>>>(deg_t, start_t, cur_t, N);
  k_fill<<<kgrid256, 256, 0, stream>>>(tgt, teid, cur_t, bucket_t, K);
  k_alpha_gather<<<(N+3)/4, 256, 0, stream>>>(tree_m, start_t, bucket_t, alpha16, N);

  // backtracking pairs
  k_fill_int<<<egrid256, 256, 0, stream>>>(aff, E, -1);
  k_fill_int<<<1, 256, 0, stream>>>(affcnt, 1, 0);
  k_probe1<<<egrid256, 256, 0, stream>>>(edge_src, edge_dst, start_d, bucket_d, degx, E);
  k_scan<<<1, 1024, 0, stream>>>(degx, startx, curx, E);
  k_probe2<<<egrid256, 256, 0, stream>>>(edge_src, edge_dst, start_d, bucket_d,
                                         startx, pairs, aff, affE2, affcnt, E);

  // msg_input = [x_src|xe] @ Wi  (raw, E rows)
  k_mpnn<<<(E+63)/64, 256, 0, stream>>>(x_nodes, x_edges, (const u16*)0, edge_src,
                                        BTf_bp, (const float*)0, msgIn, (float*)0, E, 0);

  // 3 BP iterations; corrP double-buffered
  float* cprev = corrP0; float* ccur = corrP1;
  for (int k=1; k<=3; k++){
    int first = (k==1);
    k_corr<<<8, 256, 0, stream>>>(msgIn, P16, cprev, aff, edge_src,
                                  startx, pairs, affE2, affcnt, W_h, ccur, first);
    k_nodesum<<<(N+3)/4, 256, 0, stream>>>(msgIn, P16, alpha16, start_d, bucket_d,
                                           edge_src, aff, cprev, SA16, N, first);
    k_mpnn<<<(N+63)/64, 256, 0, stream>>>((const float*)0, (const float*)0, SA16, (const int*)0,
                                          BTf_h, (const float*)0, P16, (float*)0, N, 3);
    float* t = cprev; cprev = ccur; ccur = t;
  }
  // SA_4 = m + alpha (from msg_3 on the fly; uses P_3 and corrP_3=cprev)
  k_nodesum<<<(N+3)/4, 256, 0, stream>>>(msgIn, P16, alpha16, start_d, bucket_d,
                                         edge_src, aff, cprev, SA16, N, 0);
  // h = relu([x | SA_4] @ Wo + b)   (writes into msgIn region)
  k_mpnn<<<(N+63)/64, 256, 0, stream>>>(x_nodes, (const float*)0, SA16, (const int*)0,
                                        BTf_fo, b_o, (u16*)0, hbuf, N, 2);
  k_graph_mean<<<(G+3)/4, 256, 0, stream>>>(hbuf, gid, N, G, (float*)d_out);
}